// Round 2
// baseline (70563.660 us; speedup 1.0000x reference)
//
#include <hip/hip_runtime.h>
#include <hip/hip_bf16.h>

// MultilayerGRU: B=128, S=512, H=1024, L=2, O=1024
// Round 1: persistent cooperative kernel for the 512-step scan.
//  - weights persist in LDS (bf16, XOR-swizzled), staged once
//  - layer-pipelined: L1 runs one step behind L0 -> 2 grid barriers/iter
//  - custom 2-level global barrier (agent-scope acquire/release)

typedef __bf16 bf16;
typedef __attribute__((ext_vector_type(8))) __bf16 bf16x8;
typedef __attribute__((ext_vector_type(4))) __bf16 bf16x4;
typedef __attribute__((ext_vector_type(4))) float f32x4;

#define MFMA16(a, b, c) __builtin_amdgcn_mfma_f32_16x16x32_bf16(a, b, c, 0, 0, 0)

static __device__ __forceinline__ bf16x8 ldfrag(const bf16* p) {
  return *reinterpret_cast<const bf16x8*>(p);
}

// ---------------- weight cast ----------------
__global__ void k_cast4(const float* __restrict__ s, bf16* __restrict__ d, int n4) {
  int i = blockIdx.x * blockDim.x + threadIdx.x;
  int st = gridDim.x * blockDim.x;
  for (; i < n4; i += st) {
    float4 v = reinterpret_cast<const float4*>(s)[i];
    bf16x4 o = {(bf16)v.x, (bf16)v.y, (bf16)v.z, (bf16)v.w};
    *reinterpret_cast<bf16x4*>(d + (size_t)i * 4) = o;
  }
}

// ---------------- gx0 = x @ Wx0^T + bh0 ----------------
__global__ __launch_bounds__(256) void k_gx0(const float* __restrict__ x,
                                             const bf16* __restrict__ wx0,
                                             const float* __restrict__ bh,
                                             bf16* __restrict__ gx0) {
  const int lane = threadIdx.x & 63;
  const int gw = blockIdx.x * 4 + (threadIdx.x >> 6);
  const int NT = 3072 / 64;  // 48
  const int tm = gw / NT, tn = gw % NT;
  const int m0 = tm * 64, n0 = tn * 64;
  const int r = lane & 15, kq = lane >> 4;
  f32x4 acc[4][4] = {};
  for (int k0 = 0; k0 < 1024; k0 += 32) {
    const int k = k0 + kq * 8;
    bf16x8 a[4], b[4];
#pragma unroll
    for (int mi = 0; mi < 4; ++mi) {
      const int m = m0 + mi * 16 + r;
      const int bb = m & 127, s = m >> 7;
      const float* xp = x + ((size_t)(bb * 512 + s)) * 1024 + k;
      float4 lo = *reinterpret_cast<const float4*>(xp);
      float4 hi = *reinterpret_cast<const float4*>(xp + 4);
      bf16x8 av;
      av[0] = (bf16)lo.x; av[1] = (bf16)lo.y; av[2] = (bf16)lo.z; av[3] = (bf16)lo.w;
      av[4] = (bf16)hi.x; av[5] = (bf16)hi.y; av[6] = (bf16)hi.z; av[7] = (bf16)hi.w;
      a[mi] = av;
    }
#pragma unroll
    for (int ni = 0; ni < 4; ++ni)
      b[ni] = ldfrag(wx0 + (size_t)(n0 + ni * 16 + r) * 1024 + k);
#pragma unroll
    for (int mi = 0; mi < 4; ++mi)
#pragma unroll
      for (int ni = 0; ni < 4; ++ni) acc[mi][ni] = MFMA16(a[mi], b[ni], acc[mi][ni]);
  }
#pragma unroll
  for (int mi = 0; mi < 4; ++mi) {
#pragma unroll
    for (int j = 0; j < 4; ++j) {
      const int m = m0 + mi * 16 + kq * 4 + j;
#pragma unroll
      for (int ni = 0; ni < 4; ++ni) {
        const int col = n0 + ni * 16 + r;
        gx0[(size_t)m * 3072 + col] = (bf16)(acc[mi][ni][j] + bh[col]);
      }
    }
  }
}

// ---------------- persistent GRU scan ----------------
struct GruParams {
  const float* Wx;
  const float* Wh;
  const float* bh;
  const bf16* gx0;
  bf16* h0b0;
  bf16* h0b1;
  float* h0m;
  float* h1m;
  bf16* h1seq;  // 513 slots of [128][1024]
  float* z0;
  float* z1;
  bf16* rh0;
  bf16* rh1;
  int* bar;
};

__device__ __forceinline__ void gbar(int* bar, int gen) {
  __syncthreads();
  if (threadIdx.x == 0) {
    __threadfence();
    const int g = blockIdx.x & 7;
    const int old = atomicAdd(bar + g * 32, 1);
    if (old == gen * 32 + 31) {
      const int o2 = atomicAdd(bar + 256, 1);
      if (o2 == gen * 8 + 7)
        __hip_atomic_store(bar + 288, gen + 1, __ATOMIC_RELEASE, __HIP_MEMORY_SCOPE_AGENT);
    }
    while (__hip_atomic_load(bar + 288, __ATOMIC_ACQUIRE, __HIP_MEMORY_SCOPE_AGENT) < gen + 1)
      __builtin_amdgcn_s_sleep(2);
    __threadfence();
  }
  __syncthreads();
}

__device__ __forceinline__ void stage8(char* dst_base, int c, int rowbytes, int k8,
                                       const float* src) {
  const float4 f0 = *reinterpret_cast<const float4*>(src);
  const float4 f1 = *reinterpret_cast<const float4*>(src + 4);
  bf16x8 v;
  v[0] = (bf16)f0.x; v[1] = (bf16)f0.y; v[2] = (bf16)f0.z; v[3] = (bf16)f0.w;
  v[4] = (bf16)f1.x; v[5] = (bf16)f1.y; v[6] = (bf16)f1.z; v[7] = (bf16)f1.w;
  *reinterpret_cast<bf16x8*>(dst_base + (size_t)c * rowbytes + (((k8 * 2) ^ ((c & 7) << 4)))) = v;
}

template <int KB>
__device__ __forceinline__ void mm_pass(const bf16* __restrict__ A, const char* lds_base,
                                        int kloff, f32x4& acc0, f32x4& acc1,
                                        int m0, int r, int kq) {
  const char* bp = lds_base + r * KB;
#pragma unroll 4
  for (int k0 = 0; k0 < 1024; k0 += 32) {
    const int k = k0 + kq * 8;
    const bf16x8 a0 = ldfrag(A + (size_t)(m0 + r) * 1024 + k);
    const bf16x8 a1 = ldfrag(A + (size_t)(m0 + 16 + r) * 1024 + k);
    const bf16x8 b =
        *reinterpret_cast<const bf16x8*>(bp + ((((kloff + k) * 2) ^ ((r & 7) << 4))));
    acc0 = MFMA16(a0, b, acc0);
    acc1 = MFMA16(a1, b, acc1);
  }
}

__global__ void __launch_bounds__(256, 1) k_gru(GruParams P) {
  extern __shared__ char lds[];
  const int w = blockIdx.x;
  const int tid = threadIdx.x;
  const size_t HB = 128 * 1024;

  // ---- stage weights into LDS (once) ----
  if (w < 128) {
    // phase A: L0 z/r cols [w*16, w*16+16) of 2048 ; K=1024 (Wh0)
    const int c0 = w * 16;
    for (int ch = tid; ch < 2048; ch += 256) {
      const int c = ch >> 7, k8 = (ch & 127) * 8;
      const int col = c0 + c;
      const float* s = P.Wh + ((size_t)((col >> 10) * 1024 + (col & 1023))) * 1024 + k8;
      stage8(lds, c, 2048, k8, s);
    }
  } else {
    // phase A: L1 z/r cols ; K=2048 ([Wx1 | Wh1])
    const int c0 = (w - 128) * 16;
    for (int ch = tid; ch < 4096; ch += 256) {
      const int c = ch >> 8, k8 = (ch & 255) * 8;
      const int col = c0 + c;
      const int gr = col >> 10, row = col & 1023;
      const float* s = (k8 < 1024)
                           ? P.Wx + ((size_t)((3 + gr) * 1024 + row)) * 1024 + k8
                           : P.Wh + ((size_t)((3 + gr) * 1024 + row)) * 1024 + (k8 - 1024);
      stage8(lds, c, 4096, k8, s);
    }
  }
  if (w < 64) {
    // phase B: L0 g cols [w*16) ; K=1024 (Wh0g)
    const int c0 = w * 16;
    for (int ch = tid; ch < 2048; ch += 256) {
      const int c = ch >> 7, k8 = (ch & 127) * 8;
      const float* s = P.Wh + ((size_t)(2 * 1024 + c0 + c)) * 1024 + k8;
      stage8(lds + 32768, c, 2048, k8, s);
    }
  } else if (w < 128) {
    // phase B: L1 g cols [(w-64)*16) ; K=2048 ([Wx1g | Wh1g])
    const int c0 = (w - 64) * 16;
    for (int ch = tid; ch < 4096; ch += 256) {
      const int c = ch >> 8, k8 = (ch & 255) * 8;
      const int row = c0 + c;
      const float* s = (k8 < 1024) ? P.Wx + ((size_t)(5 * 1024 + row)) * 1024 + k8
                                   : P.Wh + ((size_t)(5 * 1024 + row)) * 1024 + (k8 - 1024);
      stage8(lds + 32768, c, 4096, k8, s);
    }
  }
  __syncthreads();

  const int r = tid & 15, kq = (tid >> 4) & 3, m0 = (tid >> 6) * 32;
  int gen = 0;

  for (int i = 0; i <= 512; ++i) {
    const bf16* h0prev = (i & 1) ? P.h0b1 : P.h0b0;
    bf16* h0next = (i & 1) ? P.h0b0 : P.h0b1;

    // ---------------- phase A: z/r gates ----------------
    if (w < 128) {
      if (i < 512) {
        f32x4 acc0 = {}, acc1 = {};
        mm_pass<2048>(h0prev, lds, 0, acc0, acc1, m0, r, kq);
        const int col = w * 16 + r;
        const bf16* gx = P.gx0 + (size_t)i * 128 * 3072 + col;
        if (w < 64) {  // z0
#pragma unroll
          for (int f = 0; f < 2; ++f) {
            const f32x4 a = f ? acc1 : acc0;
#pragma unroll
            for (int j = 0; j < 4; ++j) {
              const int m = m0 + f * 16 + kq * 4 + j;
              const float pre = a[j] + (float)gx[(size_t)m * 3072];
              P.z0[(size_t)m * 1024 + col] = 1.f / (1.f + __expf(-pre));
            }
          }
        } else {  // r0 -> rh0
          const int hc = col - 1024;
#pragma unroll
          for (int f = 0; f < 2; ++f) {
            const f32x4 a = f ? acc1 : acc0;
#pragma unroll
            for (int j = 0; j < 4; ++j) {
              const int m = m0 + f * 16 + kq * 4 + j;
              const float pre = a[j] + (float)gx[(size_t)m * 3072];
              const float sg = 1.f / (1.f + __expf(-pre));
              P.rh0[(size_t)m * 1024 + hc] = (bf16)(sg * P.h0m[(size_t)m * 1024 + hc]);
            }
          }
        }
      }
    } else {
      if (i >= 1) {  // L1 step t1 = i-1
        f32x4 acc0 = {}, acc1 = {};
        mm_pass<4096>(h0prev, lds, 0, acc0, acc1, m0, r, kq);
        mm_pass<4096>(P.h1seq + (size_t)(i - 1) * HB, lds, 1024, acc0, acc1, m0, r, kq);
        const int col = (w - 128) * 16 + r;
        const float bias = P.bh[3072 + col];
        if (col < 1024) {  // z1
#pragma unroll
          for (int f = 0; f < 2; ++f) {
            const f32x4 a = f ? acc1 : acc0;
#pragma unroll
            for (int j = 0; j < 4; ++j) {
              const int m = m0 + f * 16 + kq * 4 + j;
              P.z1[(size_t)m * 1024 + col] = 1.f / (1.f + __expf(-(a[j] + bias)));
            }
          }
        } else {  // r1 -> rh1
          const int hc = col - 1024;
#pragma unroll
          for (int f = 0; f < 2; ++f) {
            const f32x4 a = f ? acc1 : acc0;
#pragma unroll
            for (int j = 0; j < 4; ++j) {
              const int m = m0 + f * 16 + kq * 4 + j;
              const float sg = 1.f / (1.f + __expf(-(a[j] + bias)));
              P.rh1[(size_t)m * 1024 + hc] = (bf16)(sg * P.h1m[(size_t)m * 1024 + hc]);
            }
          }
        }
      }
    }
    gbar(P.bar, gen++);

    // ---------------- phase B: g gate + state update ----------------
    if (w < 64) {
      if (i < 512) {
        f32x4 acc0 = {}, acc1 = {};
        mm_pass<2048>(P.rh0, lds + 32768, 0, acc0, acc1, m0, r, kq);
        const int col = w * 16 + r;
        const bf16* gx = P.gx0 + (size_t)i * 128 * 3072 + 2048 + col;
#pragma unroll
        for (int f = 0; f < 2; ++f) {
          const f32x4 a = f ? acc1 : acc0;
#pragma unroll
          for (int j = 0; j < 4; ++j) {
            const int m = m0 + f * 16 + kq * 4 + j;
            const float g = tanhf(a[j] + (float)gx[(size_t)m * 3072]);
            const size_t idx = (size_t)m * 1024 + col;
            const float z = P.z0[idx];
            const float hn = z * P.h0m[idx] + (1.f - z) * g;
            P.h0m[idx] = hn;
            h0next[idx] = (bf16)hn;
          }
        }
      }
    } else if (w < 128) {
      if (i >= 1) {
        f32x4 acc0 = {}, acc1 = {};
        mm_pass<4096>(h0prev, lds + 32768, 0, acc0, acc1, m0, r, kq);
        mm_pass<4096>(P.rh1, lds + 32768, 1024, acc0, acc1, m0, r, kq);
        const int col = (w - 64) * 16 + r;
        const float bias = P.bh[5120 + col];
#pragma unroll
        for (int f = 0; f < 2; ++f) {
          const f32x4 a = f ? acc1 : acc0;
#pragma unroll
          for (int j = 0; j < 4; ++j) {
            const int m = m0 + f * 16 + kq * 4 + j;
            const float g = tanhf(a[j] + bias);
            const size_t idx = (size_t)m * 1024 + col;
            const float z = P.z1[idx];
            const float hn = z * P.h1m[idx] + (1.f - z) * g;
            P.h1m[idx] = hn;
            P.h1seq[(size_t)i * HB + idx] = (bf16)hn;  // slot i = h1[i-1]
          }
        }
      }
    }
    gbar(P.bar, gen++);
  }
}

// ---------------- final output GEMM: h1_all @ Why^T + by ----------------
__global__ __launch_bounds__(256) void k_out(const bf16* __restrict__ h1, const bf16* __restrict__ why,
                                             const float* __restrict__ by, float* __restrict__ out) {
  const int lane = threadIdx.x & 63;
  const int gw = blockIdx.x * 4 + (threadIdx.x >> 6);
  const int tm = gw >> 4, tn = gw & 15;
  const int m0 = tm * 64, n0 = tn * 64;
  const int r = lane & 15, kq = lane >> 4;
  f32x4 acc[4][4] = {};
  for (int k0 = 0; k0 < 1024; k0 += 32) {
    const int k = k0 + kq * 8;
    bf16x8 a[4], b[4];
#pragma unroll
    for (int mi = 0; mi < 4; ++mi) a[mi] = ldfrag(h1 + (size_t)(m0 + mi * 16 + r) * 1024 + k);
#pragma unroll
    for (int ni = 0; ni < 4; ++ni) b[ni] = ldfrag(why + (size_t)(n0 + ni * 16 + r) * 1024 + k);
#pragma unroll
    for (int mi = 0; mi < 4; ++mi)
#pragma unroll
      for (int ni = 0; ni < 4; ++ni) acc[mi][ni] = MFMA16(a[mi], b[ni], acc[mi][ni]);
  }
#pragma unroll
  for (int mi = 0; mi < 4; ++mi) {
#pragma unroll
    for (int j = 0; j < 4; ++j) {
      const int m = m0 + mi * 16 + kq * 4 + j;
      const int s = m >> 7, bb = m & 127;
#pragma unroll
      for (int ni = 0; ni < 4; ++ni) {
        const int col = n0 + ni * 16 + r;
        out[((size_t)bb * 512 + s) * 1024 + col] = acc[mi][ni][j] + by[col];
      }
    }
  }
}

// ---------------- hidden state epilogue ----------------
__global__ void k_hidden(const float* __restrict__ h0m, const float* __restrict__ h1m,
                         float* __restrict__ out) {
  const int i = blockIdx.x * blockDim.x + threadIdx.x;
  const int b = i >> 10, h = i & 1023;
  out[(size_t)b * 2048 + h] = h0m[i];
  out[(size_t)b * 2048 + 1024 + h] = h1m[i];
}

extern "C" void kernel_launch(void* const* d_in, const int* in_sizes, int n_in,
                              void* d_out, int out_size, void* d_ws, size_t ws_size,
                              hipStream_t stream) {
  const float* x = (const float*)d_in[0];
  const float* Wx = (const float*)d_in[1];
  const float* Wh = (const float*)d_in[2];
  const float* bh = (const float*)d_in[3];
  const float* Why = (const float*)d_in[4];
  const float* by = (const float*)d_in[5];
  float* out = (float*)d_out;

  char* ws = (char*)d_ws;
  size_t off = 0;
  auto alloc = [&](size_t bytes) -> void* {
    void* p = ws + off;
    off += (bytes + 255) & ~(size_t)255;
    return p;
  };
  const size_t HB = (size_t)128 * 1024;
  bf16* Wxb = (bf16*)alloc((size_t)3 * 1024 * 1024 * 2);  // layer-0 Wx (for gx0)
  bf16* Whyb = (bf16*)alloc((size_t)1024 * 1024 * 2);
  bf16* gx0 = (bf16*)alloc((size_t)512 * 128 * 3072 * 2);
  bf16* h1seq = (bf16*)alloc((size_t)513 * HB * 2);
  bf16* h0b0 = (bf16*)alloc(HB * 2);
  bf16* h0b1 = (bf16*)alloc(HB * 2);
  float* h0m = (float*)alloc(HB * 4);
  float* h1m = (float*)alloc(HB * 4);
  float* z0 = (float*)alloc(HB * 4);
  float* z1 = (float*)alloc(HB * 4);
  bf16* rh0 = (bf16*)alloc(HB * 2);
  bf16* rh1 = (bf16*)alloc(HB * 2);
  int* bar = (int*)alloc(4096);
  (void)ws_size;

  hipFuncSetAttribute((const void*)k_gru, hipFuncAttributeMaxDynamicSharedMemorySize, 98304);

  k_cast4<<<512, 256, 0, stream>>>(Wx, Wxb, (3 * 1024 * 1024) / 4);
  k_cast4<<<256, 256, 0, stream>>>(Why, Whyb, (1024 * 1024) / 4);
  hipMemsetAsync(h0b0, 0, HB * 2, stream);
  hipMemsetAsync(h0m, 0, HB * 4, stream);
  hipMemsetAsync(h1m, 0, HB * 4, stream);
  hipMemsetAsync(h1seq, 0, HB * 2, stream);  // slot 0 = h1[-1] = 0
  hipMemsetAsync(bar, 0, 4096, stream);

  k_gx0<<<12288, 256, 0, stream>>>(x, Wxb, bh, gx0);

  GruParams gp{Wx, Wh, bh, gx0, h0b0, h0b1, h0m, h1m, h1seq, z0, z1, rh0, rh1, bar};
  void* kargs[] = {&gp};
  hipLaunchCooperativeKernel((void*)k_gru, dim3(256), dim3(256), kargs, 98304, stream);

  k_out<<<4096, 256, 0, stream>>>(h1seq + HB, Whyb, by, out);
  k_hidden<<<512, 256, 0, stream>>>(h0m, h1m, out + (size_t)128 * 512 * 1024);
}

// Round 3
// 25447.581 us; speedup vs baseline: 2.7729x; 2.7729x over previous
//
#include <hip/hip_runtime.h>
#include <hip/hip_bf16.h>

// MultilayerGRU: B=128, S=512, H=1024, L=2, O=1024
// Round 3: persistent cooperative scan, z/h state in registers, transposed gx0,
// relaxed-poll barrier, role-specialized WGs, output GEMM folded into the scan.

typedef __bf16 bf16;
typedef __attribute__((ext_vector_type(8))) __bf16 bf16x8;
typedef __attribute__((ext_vector_type(4))) __bf16 bf16x4;
typedef __attribute__((ext_vector_type(4))) float f32x4;

#define MFMA16(a, b, c) __builtin_amdgcn_mfma_f32_16x16x32_bf16(a, b, c, 0, 0, 0)

static __device__ __forceinline__ bf16x8 ldfrag(const bf16* p) {
  return *reinterpret_cast<const bf16x8*>(p);
}
static __device__ __forceinline__ float sigmf(float x) { return 1.f / (1.f + __expf(-x)); }

// ---------------- weight cast (layer-0 Wx only, for gx0 GEMM) ----------------
__global__ void k_cast4(const float* __restrict__ s, bf16* __restrict__ d, int n4) {
  int i = blockIdx.x * blockDim.x + threadIdx.x;
  int st = gridDim.x * blockDim.x;
  for (; i < n4; i += st) {
    float4 v = reinterpret_cast<const float4*>(s)[i];
    bf16x4 o = {(bf16)v.x, (bf16)v.y, (bf16)v.z, (bf16)v.w};
    *reinterpret_cast<bf16x4*>(d + (size_t)i * 4) = o;
  }
}

// ---------------- gx0T[s][col][b] = (x @ Wx0^T + bh0) transposed ----------------
__global__ __launch_bounds__(256) void k_gx0T(const float* __restrict__ x,
                                              const bf16* __restrict__ wx0,
                                              const float* __restrict__ bh,
                                              bf16* __restrict__ gx0T) {
  const int lane = threadIdx.x & 63;
  const int gw = blockIdx.x * 4 + (threadIdx.x >> 6);
  const int NT = 3072 / 64;  // 48
  const int tm = gw / NT, tn = gw % NT;
  const int m0 = tm * 64, n0 = tn * 64;
  const int r = lane & 15, kq = lane >> 4;
  f32x4 acc[4][4] = {};
  for (int k0 = 0; k0 < 1024; k0 += 32) {
    const int k = k0 + kq * 8;
    bf16x8 a[4], b[4];
#pragma unroll
    for (int mi = 0; mi < 4; ++mi) {
      const int m = m0 + mi * 16 + r;
      const int bb = m & 127, s = m >> 7;
      const float* xp = x + ((size_t)(bb * 512 + s)) * 1024 + k;
      float4 lo = *reinterpret_cast<const float4*>(xp);
      float4 hi = *reinterpret_cast<const float4*>(xp + 4);
      bf16x8 av;
      av[0] = (bf16)lo.x; av[1] = (bf16)lo.y; av[2] = (bf16)lo.z; av[3] = (bf16)lo.w;
      av[4] = (bf16)hi.x; av[5] = (bf16)hi.y; av[6] = (bf16)hi.z; av[7] = (bf16)hi.w;
      a[mi] = av;
    }
#pragma unroll
    for (int ni = 0; ni < 4; ++ni)
      b[ni] = ldfrag(wx0 + (size_t)(n0 + ni * 16 + r) * 1024 + k);
#pragma unroll
    for (int mi = 0; mi < 4; ++mi)
#pragma unroll
      for (int ni = 0; ni < 4; ++ni) acc[mi][ni] = MFMA16(a[mi], b[ni], acc[mi][ni]);
  }
#pragma unroll
  for (int mi = 0; mi < 4; ++mi) {
#pragma unroll
    for (int ni = 0; ni < 4; ++ni) {
      const int col = n0 + ni * 16 + r;
      const float bias = bh[col];
      bf16x4 v;
#pragma unroll
      for (int j = 0; j < 4; ++j) v[j] = (bf16)(acc[mi][ni][j] + bias);
      const int m = m0 + mi * 16 + kq * 4;  // 4 consecutive b's (same s)
      const int s = m >> 7, bb = m & 127;
      *reinterpret_cast<bf16x4*>(gx0T + ((size_t)s * 3072 + col) * 128 + bb) = v;
    }
  }
}

// ---------------- persistent GRU scan ----------------
struct GP {
  const float* Wx;
  const float* Wh;
  const float* bh;
  const float* by;
  const float* Why;
  const bf16* gx0T;
  bf16* h0b0;
  bf16* h0b1;
  bf16* rh0;
  bf16* rh1;
  bf16* h1seq;  // 513 slots of [128][1024]
  float* out;
  int* bar;
};

__device__ __forceinline__ void gbar(int* bar, int gen) {
  __syncthreads();
  if (threadIdx.x == 0) {
    __threadfence();  // release my writes to device-coherence point
    const int g = blockIdx.x & 7;
    const int old = atomicAdd(bar + g * 32, 1);
    if (old == gen * 32 + 31) {
      const int o2 = atomicAdd(bar + 256, 1);
      if (o2 == gen * 8 + 7)
        __hip_atomic_store(bar + 288, gen + 1, __ATOMIC_RELEASE, __HIP_MEMORY_SCOPE_AGENT);
    }
    // relaxed poll: no per-iteration cache invalidation
    while (__hip_atomic_load(bar + 288, __ATOMIC_RELAXED, __HIP_MEMORY_SCOPE_AGENT) < gen + 1)
      __builtin_amdgcn_s_sleep(2);
    __threadfence();  // acquire side: invalidate stale caches once
  }
  __syncthreads();
}

__device__ __forceinline__ void stage_row8(char* dst, int row, int rb, int k8,
                                           const float* __restrict__ src) {
  const float4 f0 = *reinterpret_cast<const float4*>(src);
  const float4 f1 = *reinterpret_cast<const float4*>(src + 4);
  bf16x8 v;
  v[0] = (bf16)f0.x; v[1] = (bf16)f0.y; v[2] = (bf16)f0.z; v[3] = (bf16)f0.w;
  v[4] = (bf16)f1.x; v[5] = (bf16)f1.y; v[6] = (bf16)f1.z; v[7] = (bf16)f1.w;
  *reinterpret_cast<bf16x8*>(dst + (size_t)row * rb + ((k8 * 2) ^ ((row & 7) << 4))) = v;
}

template <int MT, int NT, int RB>
__device__ __forceinline__ void mmA(const bf16* __restrict__ A, const char* __restrict__ ldsb,
                                    const int kloff, f32x4 (&acc)[MT][NT], const int m0,
                                    const int r, const int kq) {
#pragma unroll 8
  for (int k0 = 0; k0 < 1024; k0 += 32) {
    const int k = k0 + kq * 8;
    bf16x8 a[MT];
#pragma unroll
    for (int mi = 0; mi < MT; ++mi)
      a[mi] = ldfrag(A + (size_t)(m0 + mi * 16 + r) * 1024 + k);
#pragma unroll
    for (int nt = 0; nt < NT; ++nt) {
      const bf16x8 b = *reinterpret_cast<const bf16x8*>(
          ldsb + (size_t)(nt * 16 + r) * RB + (((kloff + k) * 2) ^ ((r & 7) << 4)));
#pragma unroll
      for (int mi = 0; mi < MT; ++mi) acc[mi][nt] = MFMA16(a[mi], b, acc[mi][nt]);
    }
  }
}

__global__ void __launch_bounds__(256, 1) k_gru(GP P) {
  extern __shared__ char lds[];
  const int w = blockIdx.x;
  const int tid = threadIdx.x;
  const int r = tid & 15, kq = (tid >> 4) & 3, wv = tid >> 6;
  const size_t HB = 131072;  // 128*1024

  // ---- role geometry ----
  // w in [0,64):    L0   : cols c0=w*16 (z,r,g), M=128 (MT=2)
  // w in [64,192):  L1zg : idx=w-64, mh=idx>>6, c0=(idx&63)*16, M-half (MT=1)
  // w in [192,224): L1r  : c0=(w-192)*32 (NT=2), M=128 (MT=2)
  // w in [224,256): OUT  : c0=(w-224)*32 (NT=2), M=128 (MT=2)
  int c0 = 0, mh = 0;
  if (w < 64) c0 = w * 16;
  else if (w < 192) { mh = (w - 64) >> 6; c0 = ((w - 64) & 63) * 16; }
  else if (w < 224) c0 = (w - 192) * 32;
  else c0 = (w - 224) * 32;

  // ---- stage weights into LDS (once, f32 -> bf16, XOR-swizzled) ----
  if (w < 64) {
    for (int ch = tid; ch < 32 * 128; ch += 256) {  // z,r slices: rows 0..31, K=1024
      const int row = ch >> 7, k8 = (ch & 127) * 8;
      const int gate = row >> 4, col = c0 + (row & 15);
      stage_row8(lds, row, 2048, k8, P.Wh + ((size_t)(gate * 1024 + col)) * 1024 + k8);
    }
    for (int ch = tid; ch < 16 * 128; ch += 256) {  // g slice
      const int row = ch >> 7, k8 = (ch & 127) * 8;
      stage_row8(lds + 65536, row, 2048, k8,
                 P.Wh + ((size_t)(2 * 1024 + c0 + row)) * 1024 + k8);
    }
  } else if (w < 192) {
    for (int ch = tid; ch < 16 * 256; ch += 256) {  // z slice, K=2048 concat
      const int row = ch >> 8, k8 = (ch & 255) * 8;
      const int col = c0 + row;
      const float* s = (k8 < 1024) ? P.Wx + ((size_t)(3 * 1024 + col)) * 1024 + k8
                                   : P.Wh + ((size_t)(3 * 1024 + col)) * 1024 + (k8 - 1024);
      stage_row8(lds, row, 4096, k8, s);
    }
    for (int ch = tid; ch < 16 * 256; ch += 256) {  // g slice
      const int row = ch >> 8, k8 = (ch & 255) * 8;
      const int col = c0 + row;
      const float* s = (k8 < 1024) ? P.Wx + ((size_t)(5 * 1024 + col)) * 1024 + k8
                                   : P.Wh + ((size_t)(5 * 1024 + col)) * 1024 + (k8 - 1024);
      stage_row8(lds + 65536, row, 4096, k8, s);
    }
  } else if (w < 224) {
    for (int ch = tid; ch < 32 * 256; ch += 256) {  // r slice, 32 rows, K=2048
      const int row = ch >> 8, k8 = (ch & 255) * 8;
      const int col = c0 + row;
      const float* s = (k8 < 1024) ? P.Wx + ((size_t)(4 * 1024 + col)) * 1024 + k8
                                   : P.Wh + ((size_t)(4 * 1024 + col)) * 1024 + (k8 - 1024);
      stage_row8(lds, row, 4096, k8, s);
    }
  } else {
    for (int ch = tid; ch < 32 * 128; ch += 256) {  // Why slice, 32 rows, K=1024
      const int row = ch >> 7, k8 = (ch & 127) * 8;
      stage_row8(lds, row, 2048, k8, P.Why + ((size_t)(c0 + row)) * 1024 + k8);
    }
  }
  __syncthreads();

  // per-role constants
  const int m0w = wv * 32;              // MT=2 roles
  const int m0z = mh * 64 + wv * 16;    // L1zg
  float bz = 0.f, bg = 0.f;             // L1zg biases
  float br[2] = {0.f, 0.f};             // L1r
  float byv[2] = {0.f, 0.f};            // OUT
  if (w >= 64 && w < 192) {
    bz = P.bh[3 * 1024 + c0 + r];
    bg = P.bh[5 * 1024 + c0 + r];
  } else if (w < 224 && w >= 192) {
#pragma unroll
    for (int nt = 0; nt < 2; ++nt) br[nt] = P.bh[4 * 1024 + c0 + nt * 16 + r];
  } else if (w >= 224) {
#pragma unroll
    for (int nt = 0; nt < 2; ++nt) byv[nt] = P.by[c0 + nt * 16 + r];
  }

  float h0reg[8] = {}, z0reg[8] = {};  // L0
  float h1reg[4] = {}, z1reg[4] = {};  // L1zg

  int gen = 0;
  for (int i = 0; i < 514; ++i) {
    const bf16* h0cur = (i & 1) ? P.h0b0 : P.h0b1;  // h0_{i-1}
    bf16* h0nxt = (i & 1) ? P.h0b1 : P.h0b0;

    // ================= phase A =================
    if (w < 64) {
      if (i < 512) {
        const bf16* gxz = P.gx0T + ((size_t)i * 3072 + c0 + r) * 128;
        const bf16* gxr = gxz + (size_t)1024 * 128;
        bf16x4 gz[2], gr[2];
#pragma unroll
        for (int f = 0; f < 2; ++f) {
          gz[f] = *reinterpret_cast<const bf16x4*>(gxz + m0w + f * 16 + kq * 4);
          gr[f] = *reinterpret_cast<const bf16x4*>(gxr + m0w + f * 16 + kq * 4);
        }
        f32x4 acc[2][2] = {};
        mmA<2, 2, 2048>(h0cur, lds, 0, acc, m0w, r, kq);
#pragma unroll
        for (int f = 0; f < 2; ++f)
#pragma unroll
          for (int j = 0; j < 4; ++j) {
            const int ii = f * 4 + j;
            const int m = m0w + f * 16 + kq * 4 + j;
            z0reg[ii] = sigmf(acc[f][0][j] + (float)gz[f][j]);
            const float rv = sigmf(acc[f][1][j] + (float)gr[f][j]);
            P.rh0[(size_t)m * 1024 + c0 + r] = (bf16)(rv * h0reg[ii]);
          }
      }
    } else if (w < 192) {
      if (i >= 1 && i <= 512) {
        f32x4 acc[1][1] = {};
        mmA<1, 1, 4096>(h0cur, lds, 0, acc, m0z, r, kq);
        mmA<1, 1, 4096>(P.h1seq + (size_t)(i - 1) * HB, lds, 1024, acc, m0z, r, kq);
#pragma unroll
        for (int j = 0; j < 4; ++j) z1reg[j] = sigmf(acc[0][0][j] + bz);
      }
    } else if (w < 224) {
      if (i >= 1 && i <= 512) {
        const bf16* h1p = P.h1seq + (size_t)(i - 1) * HB;
        float hp[2][2][4];
#pragma unroll
        for (int f = 0; f < 2; ++f)
#pragma unroll
          for (int nt = 0; nt < 2; ++nt)
#pragma unroll
            for (int j = 0; j < 4; ++j)
              hp[f][nt][j] =
                  (float)h1p[(size_t)(m0w + f * 16 + kq * 4 + j) * 1024 + c0 + nt * 16 + r];
        f32x4 acc[2][2] = {};
        mmA<2, 2, 4096>(h0cur, lds, 0, acc, m0w, r, kq);
        mmA<2, 2, 4096>(h1p, lds, 1024, acc, m0w, r, kq);
#pragma unroll
        for (int f = 0; f < 2; ++f)
#pragma unroll
          for (int nt = 0; nt < 2; ++nt)
#pragma unroll
            for (int j = 0; j < 4; ++j) {
              const int m = m0w + f * 16 + kq * 4 + j;
              const float rv = sigmf(acc[f][nt][j] + br[nt]);
              P.rh1[(size_t)m * 1024 + c0 + nt * 16 + r] = (bf16)(rv * hp[f][nt][j]);
            }
      }
    } else {
      if (i >= 2) {
        f32x4 acc[2][2] = {};
        mmA<2, 2, 2048>(P.h1seq + (size_t)(i - 1) * HB, lds, 0, acc, m0w, r, kq);
        const int t = i - 2;
#pragma unroll
        for (int f = 0; f < 2; ++f)
#pragma unroll
          for (int nt = 0; nt < 2; ++nt)
#pragma unroll
            for (int j = 0; j < 4; ++j) {
              const int m = m0w + f * 16 + kq * 4 + j;
              P.out[((size_t)m * 512 + t) * 1024 + c0 + nt * 16 + r] =
                  acc[f][nt][j] + byv[nt];
            }
      }
    }
    gbar(P.bar, gen++);

    // ================= phase B =================
    if (w < 64) {
      if (i < 512) {
        const bf16* gxg = P.gx0T + ((size_t)i * 3072 + 2048 + c0 + r) * 128;
        bf16x4 gg[2];
#pragma unroll
        for (int f = 0; f < 2; ++f)
          gg[f] = *reinterpret_cast<const bf16x4*>(gxg + m0w + f * 16 + kq * 4);
        f32x4 acc[2][1] = {};
        mmA<2, 1, 2048>(P.rh0, lds + 65536, 0, acc, m0w, r, kq);
#pragma unroll
        for (int f = 0; f < 2; ++f)
#pragma unroll
          for (int j = 0; j < 4; ++j) {
            const int ii = f * 4 + j;
            const int m = m0w + f * 16 + kq * 4 + j;
            const float gv = tanhf(acc[f][0][j] + (float)gg[f][j]);
            const float hn = z0reg[ii] * h0reg[ii] + (1.f - z0reg[ii]) * gv;
            h0reg[ii] = hn;
            h0nxt[(size_t)m * 1024 + c0 + r] = (bf16)hn;
          }
      }
    } else if (w < 192) {
      if (i >= 1 && i <= 512) {
        f32x4 acc[1][1] = {};
        mmA<1, 1, 4096>(h0cur, lds + 65536, 0, acc, m0z, r, kq);
        mmA<1, 1, 4096>(P.rh1, lds + 65536, 1024, acc, m0z, r, kq);
#pragma unroll
        for (int j = 0; j < 4; ++j) {
          const int m = m0z + kq * 4 + j;
          const float gv = tanhf(acc[0][0][j] + bg);
          const float hn = z1reg[j] * h1reg[j] + (1.f - z1reg[j]) * gv;
          h1reg[j] = hn;
          P.h1seq[(size_t)i * HB + (size_t)m * 1024 + c0 + r] = (bf16)hn;
        }
      }
    }
    gbar(P.bar, gen++);
  }

  // ---- final hidden state from registers: out_hidden[b][layer][1024] ----
  float* hid = P.out + (size_t)128 * 512 * 1024;
  if (w < 64) {
#pragma unroll
    for (int f = 0; f < 2; ++f)
#pragma unroll
      for (int j = 0; j < 4; ++j) {
        const int m = m0w + f * 16 + kq * 4 + j;
        hid[(size_t)m * 2048 + c0 + r] = h0reg[f * 4 + j];
      }
  } else if (w < 192) {
#pragma unroll
    for (int j = 0; j < 4; ++j) {
      const int m = m0z + kq * 4 + j;
      hid[(size_t)m * 2048 + 1024 + c0 + r] = h1reg[j];
    }
  }
}

extern "C" void kernel_launch(void* const* d_in, const int* in_sizes, int n_in,
                              void* d_out, int out_size, void* d_ws, size_t ws_size,
                              hipStream_t stream) {
  const float* x = (const float*)d_in[0];
  const float* Wx = (const float*)d_in[1];
  const float* Wh = (const float*)d_in[2];
  const float* bh = (const float*)d_in[3];
  const float* Why = (const float*)d_in[4];
  const float* by = (const float*)d_in[5];
  float* out = (float*)d_out;

  char* ws = (char*)d_ws;
  size_t off = 0;
  auto alloc = [&](size_t bytes) -> void* {
    void* p = ws + off;
    off += (bytes + 255) & ~(size_t)255;
    return p;
  };
  const size_t HB = 131072;  // elems per h snapshot
  bf16* Wxb = (bf16*)alloc((size_t)3 * 1024 * 1024 * 2);          // layer-0 Wx bf16
  bf16* gx0T = (bf16*)alloc((size_t)512 * 3072 * 128 * 2);        // 384 MB
  bf16* h1seq = (bf16*)alloc((size_t)513 * HB * 2);               // ~134 MB
  bf16* h0b0 = (bf16*)alloc(HB * 2);
  bf16* h0b1 = (bf16*)alloc(HB * 2);
  bf16* rh0 = (bf16*)alloc(HB * 2);
  bf16* rh1 = (bf16*)alloc(HB * 2);
  int* bar = (int*)alloc(4096);
  (void)ws_size;

  hipFuncSetAttribute((const void*)k_gru, hipFuncAttributeMaxDynamicSharedMemorySize, 131072);

  k_cast4<<<512, 256, 0, stream>>>(Wx, Wxb, (3 * 1024 * 1024) / 4);
  hipMemsetAsync(h0b0, 0, HB * 2, stream);
  hipMemsetAsync(h0b1, 0, HB * 2, stream);
  hipMemsetAsync(h1seq, 0, HB * 2, stream);  // slot 0 = h1 initial = 0
  hipMemsetAsync(bar, 0, 4096, stream);

  k_gx0T<<<12288, 256, 0, stream>>>(x, Wxb, bh, gx0T);

  GP gp{Wx, Wh, bh, by, Why, gx0T, h0b0, h0b1, rh0, rh1, h1seq, out, bar};
  void* kargs[] = {&gp};
  hipLaunchCooperativeKernel((void*)k_gru, dim3(256), dim3(256), kargs, 131072, stream);
}

// Round 4
// 23742.224 us; speedup vs baseline: 2.9721x; 1.0718x over previous
//
#include <hip/hip_runtime.h>
#include <hip/hip_bf16.h>

// MultilayerGRU: B=128, S=512, H=1024, L=2, O=1024
// Round 4: fence-free barrier protocol.
//  - producers write activations with sc0 sc1 (write-through to LLC, L2 stays clean)
//  - release = s_waitcnt vmcnt(0) + atomic tree (no buffer_wbl2)
//  - acquire = __builtin_amdgcn_fence(ACQUIRE, "agent") (buffer_inv only)
//  - gx0T addends prefetched one phase ahead

typedef __bf16 bf16;
typedef __attribute__((ext_vector_type(8))) __bf16 bf16x8;
typedef __attribute__((ext_vector_type(4))) __bf16 bf16x4;
typedef __attribute__((ext_vector_type(4))) float f32x4;

#define MFMA16(a, b, c) __builtin_amdgcn_mfma_f32_16x16x32_bf16(a, b, c, 0, 0, 0)

static __device__ __forceinline__ bf16x8 ldfrag(const bf16* p) {
  return *reinterpret_cast<const bf16x8*>(p);
}
static __device__ __forceinline__ float sigmf(float x) { return 1.f / (1.f + __expf(-x)); }

// write-through stores: bypass L1/L2, land at the device coherence point (LLC)
static __device__ __forceinline__ void st2_llc(bf16* p, bf16 v) {
  unsigned u = (unsigned)__builtin_bit_cast(unsigned short, v);
  asm volatile("global_store_short %0, %1, off sc0 sc1" :: "v"(p), "v"(u) : "memory");
}
static __device__ __forceinline__ void st4f_llc(float* p, float v) {
  asm volatile("global_store_dword %0, %1, off sc0 sc1" :: "v"(p), "v"(v) : "memory");
}

// ---------------- weight cast (layer-0 Wx only, for gx0 GEMM) ----------------
__global__ void k_cast4(const float* __restrict__ s, bf16* __restrict__ d, int n4) {
  int i = blockIdx.x * blockDim.x + threadIdx.x;
  int st = gridDim.x * blockDim.x;
  for (; i < n4; i += st) {
    float4 v = reinterpret_cast<const float4*>(s)[i];
    bf16x4 o = {(bf16)v.x, (bf16)v.y, (bf16)v.z, (bf16)v.w};
    *reinterpret_cast<bf16x4*>(d + (size_t)i * 4) = o;
  }
}

// ---------------- gx0T[s][col][b] = (x @ Wx0^T + bh0) transposed ----------------
__global__ __launch_bounds__(256) void k_gx0T(const float* __restrict__ x,
                                              const bf16* __restrict__ wx0,
                                              const float* __restrict__ bh,
                                              bf16* __restrict__ gx0T) {
  const int lane = threadIdx.x & 63;
  const int gw = blockIdx.x * 4 + (threadIdx.x >> 6);
  const int NT = 3072 / 64;  // 48
  const int tm = gw / NT, tn = gw % NT;
  const int m0 = tm * 64, n0 = tn * 64;
  const int r = lane & 15, kq = lane >> 4;
  f32x4 acc[4][4] = {};
  for (int k0 = 0; k0 < 1024; k0 += 32) {
    const int k = k0 + kq * 8;
    bf16x8 a[4], b[4];
#pragma unroll
    for (int mi = 0; mi < 4; ++mi) {
      const int m = m0 + mi * 16 + r;
      const int bb = m & 127, s = m >> 7;
      const float* xp = x + ((size_t)(bb * 512 + s)) * 1024 + k;
      float4 lo = *reinterpret_cast<const float4*>(xp);
      float4 hi = *reinterpret_cast<const float4*>(xp + 4);
      bf16x8 av;
      av[0] = (bf16)lo.x; av[1] = (bf16)lo.y; av[2] = (bf16)lo.z; av[3] = (bf16)lo.w;
      av[4] = (bf16)hi.x; av[5] = (bf16)hi.y; av[6] = (bf16)hi.z; av[7] = (bf16)hi.w;
      a[mi] = av;
    }
#pragma unroll
    for (int ni = 0; ni < 4; ++ni)
      b[ni] = ldfrag(wx0 + (size_t)(n0 + ni * 16 + r) * 1024 + k);
#pragma unroll
    for (int mi = 0; mi < 4; ++mi)
#pragma unroll
      for (int ni = 0; ni < 4; ++ni) acc[mi][ni] = MFMA16(a[mi], b[ni], acc[mi][ni]);
  }
#pragma unroll
  for (int mi = 0; mi < 4; ++mi) {
#pragma unroll
    for (int ni = 0; ni < 4; ++ni) {
      const int col = n0 + ni * 16 + r;
      const float bias = bh[col];
      bf16x4 v;
#pragma unroll
      for (int j = 0; j < 4; ++j) v[j] = (bf16)(acc[mi][ni][j] + bias);
      const int m = m0 + mi * 16 + kq * 4;  // 4 consecutive b's (same s)
      const int s = m >> 7, bb = m & 127;
      *reinterpret_cast<bf16x4*>(gx0T + ((size_t)s * 3072 + col) * 128 + bb) = v;
    }
  }
}

// ---------------- persistent GRU scan ----------------
struct GP {
  const float* Wx;
  const float* Wh;
  const float* bh;
  const float* by;
  const float* Why;
  const bf16* gx0T;
  bf16* h0b0;
  bf16* h0b1;
  bf16* rh0;
  bf16* rh1;
  bf16* h1seq;  // 513 slots of [128][1024]
  float* out;
  int* bar;
};

__device__ __forceinline__ void gbar(int* bar, int gen) {
  // release: my wave's sc0sc1 stores must be complete at LLC before arriving
  asm volatile("s_waitcnt vmcnt(0)" ::: "memory");
  __syncthreads();  // all 4 waves' stores complete
  if (threadIdx.x == 0) {
    const int g = blockIdx.x & 7;
    const int old = atomicAdd(bar + g * 32, 1);
    if (old == gen * 32 + 31) {
      const int o2 = atomicAdd(bar + 256, 1);
      if (o2 == gen * 8 + 7)
        __hip_atomic_store(bar + 288, gen + 1, __ATOMIC_RELAXED, __HIP_MEMORY_SCOPE_AGENT);
    }
    while (__hip_atomic_load(bar + 288, __ATOMIC_RELAXED, __HIP_MEMORY_SCOPE_AGENT) < gen + 1)
      __builtin_amdgcn_s_sleep(2);
  }
  __syncthreads();
  // acquire: drop stale L1/L2 lines (producers wrote through to LLC)
  __builtin_amdgcn_fence(__ATOMIC_ACQUIRE, "agent");
}

__device__ __forceinline__ void stage_row8(char* dst, int row, int rb, int k8,
                                           const float* __restrict__ src) {
  const float4 f0 = *reinterpret_cast<const float4*>(src);
  const float4 f1 = *reinterpret_cast<const float4*>(src + 4);
  bf16x8 v;
  v[0] = (bf16)f0.x; v[1] = (bf16)f0.y; v[2] = (bf16)f0.z; v[3] = (bf16)f0.w;
  v[4] = (bf16)f1.x; v[5] = (bf16)f1.y; v[6] = (bf16)f1.z; v[7] = (bf16)f1.w;
  *reinterpret_cast<bf16x8*>(dst + (size_t)row * rb + ((k8 * 2) ^ ((row & 7) << 4))) = v;
}

template <int MT, int NT, int RB>
__device__ __forceinline__ void mmA(const bf16* __restrict__ A, const char* __restrict__ ldsb,
                                    const int kloff, f32x4 (&acc)[MT][NT], const int m0,
                                    const int r, const int kq) {
#pragma unroll 8
  for (int k0 = 0; k0 < 1024; k0 += 32) {
    const int k = k0 + kq * 8;
    bf16x8 a[MT];
#pragma unroll
    for (int mi = 0; mi < MT; ++mi)
      a[mi] = ldfrag(A + (size_t)(m0 + mi * 16 + r) * 1024 + k);
#pragma unroll
    for (int nt = 0; nt < NT; ++nt) {
      const bf16x8 b = *reinterpret_cast<const bf16x8*>(
          ldsb + (size_t)(nt * 16 + r) * RB + (((kloff + k) * 2) ^ ((r & 7) << 4)));
#pragma unroll
      for (int mi = 0; mi < MT; ++mi) acc[mi][nt] = MFMA16(a[mi], b, acc[mi][nt]);
    }
  }
}

__global__ void __launch_bounds__(256, 1) k_gru(GP P) {
  extern __shared__ char lds[];
  const int w = blockIdx.x;
  const int tid = threadIdx.x;
  const int r = tid & 15, kq = (tid >> 4) & 3, wv = tid >> 6;
  const size_t HB = 131072;  // 128*1024

  // ---- role geometry ----
  // w in [0,64):    L0   : cols c0=w*16 (z,r,g), M=128 (MT=2)
  // w in [64,192):  L1zg : idx=w-64, mh=idx>>6, c0=(idx&63)*16, M-half (MT=1)
  // w in [192,224): L1r  : c0=(w-192)*32 (NT=2), M=128 (MT=2)
  // w in [224,256): OUT  : c0=(w-224)*32 (NT=2), M=128 (MT=2)
  int c0 = 0, mh = 0;
  if (w < 64) c0 = w * 16;
  else if (w < 192) { mh = (w - 64) >> 6; c0 = ((w - 64) & 63) * 16; }
  else if (w < 224) c0 = (w - 192) * 32;
  else c0 = (w - 224) * 32;

  // ---- stage weights into LDS (once, f32 -> bf16, XOR-swizzled) ----
  if (w < 64) {
    for (int ch = tid; ch < 32 * 128; ch += 256) {  // z,r slices: rows 0..31, K=1024
      const int row = ch >> 7, k8 = (ch & 127) * 8;
      const int gate = row >> 4, col = c0 + (row & 15);
      stage_row8(lds, row, 2048, k8, P.Wh + ((size_t)(gate * 1024 + col)) * 1024 + k8);
    }
    for (int ch = tid; ch < 16 * 128; ch += 256) {  // g slice
      const int row = ch >> 7, k8 = (ch & 127) * 8;
      stage_row8(lds + 65536, row, 2048, k8,
                 P.Wh + ((size_t)(2 * 1024 + c0 + row)) * 1024 + k8);
    }
  } else if (w < 192) {
    for (int ch = tid; ch < 16 * 256; ch += 256) {  // z slice, K=2048 concat
      const int row = ch >> 8, k8 = (ch & 255) * 8;
      const int col = c0 + row;
      const float* s = (k8 < 1024) ? P.Wx + ((size_t)(3 * 1024 + col)) * 1024 + k8
                                   : P.Wh + ((size_t)(3 * 1024 + col)) * 1024 + (k8 - 1024);
      stage_row8(lds, row, 4096, k8, s);
    }
    for (int ch = tid; ch < 16 * 256; ch += 256) {  // g slice
      const int row = ch >> 8, k8 = (ch & 255) * 8;
      const int col = c0 + row;
      const float* s = (k8 < 1024) ? P.Wx + ((size_t)(5 * 1024 + col)) * 1024 + k8
                                   : P.Wh + ((size_t)(5 * 1024 + col)) * 1024 + (k8 - 1024);
      stage_row8(lds + 65536, row, 4096, k8, s);
    }
  } else if (w < 224) {
    for (int ch = tid; ch < 32 * 256; ch += 256) {  // r slice, 32 rows, K=2048
      const int row = ch >> 8, k8 = (ch & 255) * 8;
      const int col = c0 + row;
      const float* s = (k8 < 1024) ? P.Wx + ((size_t)(4 * 1024 + col)) * 1024 + k8
                                   : P.Wh + ((size_t)(4 * 1024 + col)) * 1024 + (k8 - 1024);
      stage_row8(lds, row, 4096, k8, s);
    }
  } else {
    for (int ch = tid; ch < 32 * 128; ch += 256) {  // Why slice, 32 rows, K=1024
      const int row = ch >> 7, k8 = (ch & 127) * 8;
      stage_row8(lds, row, 2048, k8, P.Why + ((size_t)(c0 + row)) * 1024 + k8);
    }
  }
  __syncthreads();

  // per-role constants
  const int m0w = wv * 32;              // MT=2 roles
  const int m0z = mh * 64 + wv * 16;    // L1zg
  float bz = 0.f, bg = 0.f;             // L1zg biases
  float br[2] = {0.f, 0.f};             // L1r
  float byv[2] = {0.f, 0.f};            // OUT
  if (w >= 64 && w < 192) {
    bz = P.bh[3 * 1024 + c0 + r];
    bg = P.bh[5 * 1024 + c0 + r];
  } else if (w < 224 && w >= 192) {
#pragma unroll
    for (int nt = 0; nt < 2; ++nt) br[nt] = P.bh[4 * 1024 + c0 + nt * 16 + r];
  } else if (w >= 224) {
#pragma unroll
    for (int nt = 0; nt < 2; ++nt) byv[nt] = P.by[c0 + nt * 16 + r];
  }

  float h0reg[8] = {}, z0reg[8] = {};  // L0
  float h1reg[4] = {}, z1reg[4] = {};  // L1zg

  // gx addend prefetch registers (L0 only)
  bf16x4 pz[2] = {}, pr[2] = {}, pg[2] = {};
  if (w < 64) {
    const bf16* gxz = P.gx0T + ((size_t)0 * 3072 + c0 + r) * 128;
#pragma unroll
    for (int f = 0; f < 2; ++f) {
      pz[f] = *reinterpret_cast<const bf16x4*>(gxz + m0w + f * 16 + kq * 4);
      pr[f] = *reinterpret_cast<const bf16x4*>(gxz + (size_t)1024 * 128 + m0w + f * 16 + kq * 4);
    }
  }

  int gen = 0;
  for (int i = 0; i < 514; ++i) {
    const bf16* h0cur = (i & 1) ? P.h0b0 : P.h0b1;  // h0_{i-1}
    bf16* h0nxt = (i & 1) ? P.h0b1 : P.h0b0;

    // ================= phase A =================
    if (w < 64) {
      if (i < 512) {
        // prefetch g addend for this step (consumed in phase B)
        const bf16* gxg = P.gx0T + ((size_t)i * 3072 + 2048 + c0 + r) * 128;
#pragma unroll
        for (int f = 0; f < 2; ++f)
          pg[f] = *reinterpret_cast<const bf16x4*>(gxg + m0w + f * 16 + kq * 4);
        f32x4 acc[2][2] = {};
        mmA<2, 2, 2048>(h0cur, lds, 0, acc, m0w, r, kq);
#pragma unroll
        for (int f = 0; f < 2; ++f)
#pragma unroll
          for (int j = 0; j < 4; ++j) {
            const int ii = f * 4 + j;
            const int m = m0w + f * 16 + kq * 4 + j;
            z0reg[ii] = sigmf(acc[f][0][j] + (float)pz[f][j]);
            const float rv = sigmf(acc[f][1][j] + (float)pr[f][j]);
            st2_llc(P.rh0 + (size_t)m * 1024 + c0 + r, (bf16)(rv * h0reg[ii]));
          }
      }
    } else if (w < 192) {
      if (i >= 1 && i <= 512) {
        f32x4 acc[1][1] = {};
        mmA<1, 1, 4096>(h0cur, lds, 0, acc, m0z, r, kq);
        mmA<1, 1, 4096>(P.h1seq + (size_t)(i - 1) * HB, lds, 1024, acc, m0z, r, kq);
#pragma unroll
        for (int j = 0; j < 4; ++j) z1reg[j] = sigmf(acc[0][0][j] + bz);
      }
    } else if (w < 224) {
      if (i >= 1 && i <= 512) {
        const bf16* h1p = P.h1seq + (size_t)(i - 1) * HB;
        float hp[2][2][4];
#pragma unroll
        for (int f = 0; f < 2; ++f)
#pragma unroll
          for (int nt = 0; nt < 2; ++nt)
#pragma unroll
            for (int j = 0; j < 4; ++j)
              hp[f][nt][j] =
                  (float)h1p[(size_t)(m0w + f * 16 + kq * 4 + j) * 1024 + c0 + nt * 16 + r];
        f32x4 acc[2][2] = {};
        mmA<2, 2, 4096>(h0cur, lds, 0, acc, m0w, r, kq);
        mmA<2, 2, 4096>(h1p, lds, 1024, acc, m0w, r, kq);
#pragma unroll
        for (int f = 0; f < 2; ++f)
#pragma unroll
          for (int nt = 0; nt < 2; ++nt)
#pragma unroll
            for (int j = 0; j < 4; ++j) {
              const int m = m0w + f * 16 + kq * 4 + j;
              const float rv = sigmf(acc[f][nt][j] + br[nt]);
              st2_llc(P.rh1 + (size_t)m * 1024 + c0 + nt * 16 + r, (bf16)(rv * hp[f][nt][j]));
            }
      }
    } else {
      if (i >= 2) {
        f32x4 acc[2][2] = {};
        mmA<2, 2, 2048>(P.h1seq + (size_t)(i - 1) * HB, lds, 0, acc, m0w, r, kq);
        const int t = i - 2;
#pragma unroll
        for (int f = 0; f < 2; ++f)
#pragma unroll
          for (int nt = 0; nt < 2; ++nt)
#pragma unroll
            for (int j = 0; j < 4; ++j) {
              const int m = m0w + f * 16 + kq * 4 + j;
              st4f_llc(P.out + ((size_t)m * 512 + t) * 1024 + c0 + nt * 16 + r,
                       acc[f][nt][j] + byv[nt]);
            }
      }
    }
    gbar(P.bar, gen++);

    // ================= phase B =================
    if (w < 64) {
      if (i < 512) {
        // prefetch z/r addends for step i+1 (consumed next phase A)
        if (i + 1 < 512) {
          const bf16* gxz = P.gx0T + ((size_t)(i + 1) * 3072 + c0 + r) * 128;
#pragma unroll
          for (int f = 0; f < 2; ++f) {
            pz[f] = *reinterpret_cast<const bf16x4*>(gxz + m0w + f * 16 + kq * 4);
            pr[f] =
                *reinterpret_cast<const bf16x4*>(gxz + (size_t)1024 * 128 + m0w + f * 16 + kq * 4);
          }
        }
        f32x4 acc[2][1] = {};
        mmA<2, 1, 2048>(P.rh0, lds + 65536, 0, acc, m0w, r, kq);
#pragma unroll
        for (int f = 0; f < 2; ++f)
#pragma unroll
          for (int j = 0; j < 4; ++j) {
            const int ii = f * 4 + j;
            const int m = m0w + f * 16 + kq * 4 + j;
            const float gv = tanhf(acc[f][0][j] + (float)pg[f][j]);
            const float hn = z0reg[ii] * h0reg[ii] + (1.f - z0reg[ii]) * gv;
            h0reg[ii] = hn;
            st2_llc(h0nxt + (size_t)m * 1024 + c0 + r, (bf16)hn);
          }
      }
    } else if (w < 192) {
      if (i >= 1 && i <= 512) {
        f32x4 acc[1][1] = {};
        mmA<1, 1, 4096>(h0cur, lds + 65536, 0, acc, m0z, r, kq);
        mmA<1, 1, 4096>(P.rh1, lds + 65536, 1024, acc, m0z, r, kq);
#pragma unroll
        for (int j = 0; j < 4; ++j) {
          const int m = m0z + kq * 4 + j;
          const float gv = tanhf(acc[0][0][j] + bg);
          const float hn = z1reg[j] * h1reg[j] + (1.f - z1reg[j]) * gv;
          h1reg[j] = hn;
          st2_llc(P.h1seq + (size_t)i * HB + (size_t)m * 1024 + c0 + r, (bf16)hn);
        }
      }
    }
    gbar(P.bar, gen++);
  }

  // ---- final hidden state from registers: out_hidden[b][layer][1024] ----
  float* hid = P.out + (size_t)128 * 512 * 1024;
  if (w < 64) {
#pragma unroll
    for (int f = 0; f < 2; ++f)
#pragma unroll
      for (int j = 0; j < 4; ++j) {
        const int m = m0w + f * 16 + kq * 4 + j;
        hid[(size_t)m * 2048 + c0 + r] = h0reg[f * 4 + j];
      }
  } else if (w < 192) {
#pragma unroll
    for (int j = 0; j < 4; ++j) {
      const int m = m0z + kq * 4 + j;
      hid[(size_t)m * 2048 + 1024 + c0 + r] = h1reg[j];
    }
  }
}

extern "C" void kernel_launch(void* const* d_in, const int* in_sizes, int n_in,
                              void* d_out, int out_size, void* d_ws, size_t ws_size,
                              hipStream_t stream) {
  const float* x = (const float*)d_in[0];
  const float* Wx = (const float*)d_in[1];
  const float* Wh = (const float*)d_in[2];
  const float* bh = (const float*)d_in[3];
  const float* Why = (const float*)d_in[4];
  const float* by = (const float*)d_in[5];
  float* out = (float*)d_out;

  char* ws = (char*)d_ws;
  size_t off = 0;
  auto alloc = [&](size_t bytes) -> void* {
    void* p = ws + off;
    off += (bytes + 255) & ~(size_t)255;
    return p;
  };
  const size_t HB = 131072;  // elems per h snapshot
  bf16* Wxb = (bf16*)alloc((size_t)3 * 1024 * 1024 * 2);          // layer-0 Wx bf16
  bf16* gx0T = (bf16*)alloc((size_t)512 * 3072 * 128 * 2);        // 384 MB
  bf16* h1seq = (bf16*)alloc((size_t)513 * HB * 2);               // ~134 MB
  bf16* h0b0 = (bf16*)alloc(HB * 2);
  bf16* h0b1 = (bf16*)alloc(HB * 2);
  bf16* rh0 = (bf16*)alloc(HB * 2);
  bf16* rh1 = (bf16*)alloc(HB * 2);
  int* bar = (int*)alloc(4096);
  (void)ws_size;

  hipFuncSetAttribute((const void*)k_gru, hipFuncAttributeMaxDynamicSharedMemorySize, 131072);

  k_cast4<<<512, 256, 0, stream>>>(Wx, Wxb, (3 * 1024 * 1024) / 4);
  hipMemsetAsync(h0b0, 0, HB * 2, stream);
  hipMemsetAsync(h0b1, 0, HB * 2, stream);
  hipMemsetAsync(h1seq, 0, HB * 2, stream);  // slot 0 = h1 initial = 0
  hipMemsetAsync(bar, 0, 4096, stream);

  k_gx0T<<<12288, 256, 0, stream>>>(x, Wxb, bh, gx0T);

  GP gp{Wx, Wh, bh, by, Why, gx0T, h0b0, h0b1, rh0, rh1, h1seq, out, bar};
  void* kargs[] = {&gp};
  hipLaunchCooperativeKernel((void*)k_gru, dim3(256), dim3(256), kargs, 131072, stream);
}